// Round 6
// baseline (180.897 us; speedup 1.0000x reference)
//
#include <hip/hip_runtime.h>

// Rank2SymmetricTensorHead — prep + fully-fused node kernel.
// Algebra (proven absmax 0.0): layernorm is affine per edge =>
//   no[c][u] = invc*( lw_c*(emb[.,c].S1[u] - S2[u]) + lb_c*S3[u] )
// with S1[6][9],S2[6],S3[6] per node; per-edge mu/var from per-node
// mbar[9]+Gram[45] of emb. Then MLP(no)·W2 -> 9 outputs per node.
// K1 prep: edge bucketing (atomics) || node stats (DPP, no LDS)
// K2 fused: per block 16 nodes: edges->S_lds -> contraction->no_lds ->
//           6x8 thread-tile GEMM (VALU-bound) -> silu -> W2 -> atomic out.

#define SQ3  1.73205080756887729f
#define SQ15 3.87298334620741688f
#define SQ5  2.23606797749978970f

#define NB   16      // nodes per fused block
#define NSTR 1028    // floats per node plane in no_lds (128*8 + 4 pad -> bank-disjoint broadcasts)

__device__ __forceinline__ float dpp_sum64(float v) {
    // 64-lane sum, result valid in lane 63. Pure VALU.
    int x;
    x = __builtin_amdgcn_update_dpp(0, __float_as_int(v), 0x111, 0xF, 0xF, true); v += __int_as_float(x);
    x = __builtin_amdgcn_update_dpp(0, __float_as_int(v), 0x112, 0xF, 0xF, true); v += __int_as_float(x);
    x = __builtin_amdgcn_update_dpp(0, __float_as_int(v), 0x114, 0xF, 0xF, true); v += __int_as_float(x);
    x = __builtin_amdgcn_update_dpp(0, __float_as_int(v), 0x118, 0xF, 0xF, true); v += __int_as_float(x);
    x = __builtin_amdgcn_update_dpp(0, __float_as_int(v), 0x142, 0xA, 0xF, true); v += __int_as_float(x);
    x = __builtin_amdgcn_update_dpp(0, __float_as_int(v), 0x143, 0xC, 0xF, true); v += __int_as_float(x);
    return v;
}

__device__ __forceinline__ float dpp_sum16(float v) {
    // sum within each 16-lane row; total valid in lanes 15,31,47,63.
    int x;
    x = __builtin_amdgcn_update_dpp(0, __float_as_int(v), 0x111, 0xF, 0xF, true); v += __int_as_float(x);
    x = __builtin_amdgcn_update_dpp(0, __float_as_int(v), 0x112, 0xF, 0xF, true); v += __int_as_float(x);
    x = __builtin_amdgcn_update_dpp(0, __float_as_int(v), 0x114, 0xF, 0xF, true); v += __int_as_float(x);
    x = __builtin_amdgcn_update_dpp(0, __float_as_int(v), 0x118, 0xF, 0xF, true); v += __int_as_float(x);
    return v;
}

// blocks [0,PB): edge bucketing + per-batch node count
// blocks [PB,..): per-node stats (mbar[9] + Gram[45]), 1 wave/node, no LDS
__global__ __launch_bounds__(256)
void prep_kernel(const int* __restrict__ idx1, const int* __restrict__ batch,
                 int* __restrict__ cnt, int* __restrict__ bcnt, int* __restrict__ elist,
                 const float* __restrict__ emb, float* __restrict__ stats,
                 int slot, int E, int N, int PB)
{
    if ((int)blockIdx.x < PB) {
        const int i  = blockIdx.x * 256 + threadIdx.x;
        const int i4 = i * 4;
        if (i4 + 3 < E) {
            const int4 v = *(const int4*)&idx1[i4];
            int p;
            p = atomicAdd(&cnt[v.x], 1); if (p < slot) elist[(size_t)v.x * slot + p] = i4;
            p = atomicAdd(&cnt[v.y], 1); if (p < slot) elist[(size_t)v.y * slot + p] = i4 + 1;
            p = atomicAdd(&cnt[v.z], 1); if (p < slot) elist[(size_t)v.z * slot + p] = i4 + 2;
            p = atomicAdd(&cnt[v.w], 1); if (p < slot) elist[(size_t)v.w * slot + p] = i4 + 3;
        } else {
            for (int k2 = i4; k2 < E; ++k2) {
                const int nn = idx1[k2];
                const int p = atomicAdd(&cnt[nn], 1);
                if (p < slot) elist[(size_t)nn * slot + p] = k2;
            }
        }
        if (i < N) atomicAdd(&bcnt[batch[i]], 1);
        return;
    }
    const int lane = threadIdx.x & 63;
    const int n = ((int)blockIdx.x - PB) * 4 + (threadIdx.x >> 6);
    if (n >= N) return;

    const float* eb = emb + (size_t)n * 1152;
    float er0[9], er1[9];
    #pragma unroll
    for (int l = 0; l < 9; ++l) { er0[l] = eb[l * 128 + lane]; er1[l] = eb[l * 128 + 64 + lane]; }

    float* st = stats + (size_t)n * 56;
    #pragma unroll
    for (int l = 0; l < 9; ++l) {
        const float tot = dpp_sum64(er0[l] + er1[l]);
        if (lane == 63) st[l] = tot;
    }
    int idx = 9;
    #pragma unroll
    for (int l = 0; l < 9; ++l) {
        #pragma unroll
        for (int l2 = l; l2 < 9; ++l2) {
            const float tot = dpp_sum64(er0[l] * er0[l2] + er1[l] * er1[l2]);
            if (lane == 63) st[idx] = tot;
            ++idx;
        }
    }
}

__global__ __launch_bounds__(256)
void fused_kernel(const float* __restrict__ emb, const float* __restrict__ vec,
                  const int* __restrict__ cnt, const int* __restrict__ elist, int slot,
                  const float* __restrict__ sph_w, const float* __restrict__ stats,
                  const float* __restrict__ ln_w, const float* __restrict__ ln_b,
                  const float* __restrict__ W1, const float* __restrict__ b1,
                  const float* __restrict__ W2, const float* __restrict__ b2,
                  const int* __restrict__ batch, const int* __restrict__ bcnt,
                  float* __restrict__ out, int N)
{
    __shared__ float S_lds[NB][68];        // per node: S1[54],S2[6],S3[6], invc-scaled
    __shared__ float no_lds[NB * NSTR];    // per node [128][8] (6 used), +4 pad floats

    const int t = threadIdx.x;
    const int lane = t & 63, wv = t >> 6;
    const int nb = blockIdx.x * NB;

    // ================= phase 1: edges -> S_lds =================
    const float spw0 = sph_w[0], spw1 = sph_w[1], spw2 = sph_w[2];
    for (int q = 0; q < 4; ++q) {
        const int nid = wv * 4 + q;
        const int n = nb + nid;
        if (n >= N) break;
        const int   cntn = cnt[n];
        const int   cnE  = min(cntn, slot);
        const float invc = 1.f / (float)(cntn > 0 ? cntn : 1);
        const float inv128 = 1.f / 128.f;
        const float* st = stats + (size_t)n * 56;   // wave-uniform -> scalar loads

        float t1[9], mru = 0.f, op[6];
        #pragma unroll
        for (int l = 0; l < 9; ++l) t1[l] = 0.f;
        #pragma unroll
        for (int u = 0; u < 6; ++u) op[u] = 0.f;

        if (lane < cnE) {
            const int e = elist[(size_t)n * slot + lane];
            const float vx = vec[e * 3 + 0];
            const float vy = vec[e * 3 + 1];
            const float vz = vec[e * 3 + 2];
            const float rr = vx * vx + vy * vy + vz * vz;

            const float a1x = SQ3 * vx, a1y = SQ3 * vy, a1z = SQ3 * vz;
            const float q0 = SQ15 * vx * vy;
            const float q1 = SQ15 * vy * vz;
            const float q2 = 0.5f * SQ5 * (3.f * vz * vz - rr);
            const float q3 = SQ15 * vx * vz;
            const float q4 = 0.5f * SQ15 * (vx * vx - vy * vy);
            const float inv1 = spw1 * rsqrtf((a1x*a1x + a1y*a1y + a1z*a1z) * (1.f/3.f) + 1e-6f);
            const float inv2 = spw2 * rsqrtf((q0*q0 + q1*q1 + q2*q2 + q3*q3 + q4*q4) * (1.f/5.f) + 1e-6f);

            float sh[9];
            sh[0] = spw0 * rsqrtf(1.0f + 1e-6f);
            sh[1] = a1x * inv1; sh[2] = a1y * inv1; sh[3] = a1z * inv1;
            sh[4] = q0 * inv2;  sh[5] = q1 * inv2;  sh[6] = q2 * inv2;
            sh[7] = q3 * inv2;  sh[8] = q4 * inv2;

            float mu = 0.f;
            #pragma unroll
            for (int l = 0; l < 9; ++l) mu += sh[l] * st[l];
            mu *= inv128;

            float x2 = 0.f;
            {
                int idx = 9;
                #pragma unroll
                for (int l = 0; l < 9; ++l) {
                    x2 += st[idx] * sh[l] * sh[l]; ++idx;
                    #pragma unroll
                    for (int l2 = l + 1; l2 < 9; ++l2) {
                        x2 += st[idx] * (2.f * sh[l] * sh[l2]); ++idx;
                    }
                }
            }
            x2 *= inv128;

            const float rinv = rsqrtf(x2 - mu * mu + 1e-5f);
            #pragma unroll
            for (int l = 0; l < 9; ++l) t1[l] = rinv * sh[l];
            mru = rinv * mu;
            op[0] = vx*vx; op[1] = vx*vy; op[2] = vx*vz;
            op[3] = vy*vy; op[4] = vy*vz; op[5] = vz*vz;
        }

        #pragma unroll
        for (int u = 0; u < 6; ++u) {
            #pragma unroll
            for (int l = 0; l < 9; ++l) {
                const float tot = dpp_sum64(op[u] * t1[l]);
                if (lane == 63) S_lds[nid][u * 9 + l] = tot * invc;
            }
        }
        #pragma unroll
        for (int u = 0; u < 6; ++u) {
            const float tot = dpp_sum64(op[u] * mru);
            if (lane == 63) S_lds[nid][54 + u] = tot * invc;
        }
        #pragma unroll
        for (int u = 0; u < 6; ++u) {
            const float tot = dpp_sum64(op[u]);
            if (lane == 63) S_lds[nid][60 + u] = tot * invc;
        }
    }
    __syncthreads();

    // ================= phase 2: contraction -> no_lds =================
    {
        const int c = t & 127, hf = t >> 7;
        const float lwc = ln_w[c], lbc = ln_b[c];
        for (int q = 0; q < 8; ++q) {
            const int nid = hf * 8 + q;
            const int n = nb + nid;
            if (n >= N) break;
            const float* eb = emb + (size_t)n * 1152 + c;
            float e[9];
            #pragma unroll
            for (int l = 0; l < 9; ++l) e[l] = eb[l * 128];
            const float* Sp = &S_lds[nid][0];
            float val[6];
            #pragma unroll
            for (int u = 0; u < 6; ++u) {
                float a = 0.f;
                #pragma unroll
                for (int l = 0; l < 9; ++l) a += e[l] * Sp[u * 9 + l];
                val[u] = lwc * (a - Sp[54 + u]) + lbc * Sp[60 + u];
            }
            float* wp = &no_lds[nid * NSTR + c * 8];
            *(float4*)wp = make_float4(val[0], val[1], val[2], val[3]);
            *(float2*)(wp + 4) = make_float2(val[4], val[5]);
        }
    }
    __syncthreads();

    // ================= phase 3: MLP (6 rows x 8 cols per thread) =================
    {
        const int node = t >> 4, kg = t & 15;   // 16 lanes per node share a wave row
        const int n = nb + node;
        float acc[6][8];
        #pragma unroll
        for (int u = 0; u < 6; ++u)
            #pragma unroll
            for (int cc = 0; cc < 8; ++cc) acc[u][cc] = 0.f;

        const float* w1p = W1 + kg * 8;
        const float* nop = &no_lds[node * NSTR];
        #pragma unroll 4
        for (int c = 0; c < 128; ++c) {
            const float4 nA = *(const float4*)&nop[c * 8];
            const float2 nB = *(const float2*)&nop[c * 8 + 4];
            const float4 wA = *(const float4*)&w1p[(size_t)c * 128];
            const float4 wB = *(const float4*)&w1p[(size_t)c * 128 + 4];
            const float nv[6] = {nA.x, nA.y, nA.z, nA.w, nB.x, nB.y};
            #pragma unroll
            for (int u = 0; u < 6; ++u) {
                acc[u][0] = fmaf(nv[u], wA.x, acc[u][0]);
                acc[u][1] = fmaf(nv[u], wA.y, acc[u][1]);
                acc[u][2] = fmaf(nv[u], wA.z, acc[u][2]);
                acc[u][3] = fmaf(nv[u], wA.w, acc[u][3]);
                acc[u][4] = fmaf(nv[u], wB.x, acc[u][4]);
                acc[u][5] = fmaf(nv[u], wB.y, acc[u][5]);
                acc[u][6] = fmaf(nv[u], wB.z, acc[u][6]);
                acc[u][7] = fmaf(nv[u], wB.w, acc[u][7]);
            }
        }

        const float4 b1a = *(const float4*)&b1[kg * 8];
        const float4 b1b = *(const float4*)&b1[kg * 8 + 4];
        const float4 w2a = *(const float4*)&W2[kg * 8];
        const float4 w2b = *(const float4*)&W2[kg * 8 + 4];
        const float b1v[8] = {b1a.x, b1a.y, b1a.z, b1a.w, b1b.x, b1b.y, b1b.z, b1b.w};
        const float w2v[8] = {w2a.x, w2a.y, w2a.z, w2a.w, w2b.x, w2b.y, w2b.z, w2b.w};

        float sv[6];
        #pragma unroll
        for (int u = 0; u < 6; ++u) {
            float s = 0.f;
            #pragma unroll
            for (int cc = 0; cc < 8; ++cc) {
                const float z = acc[u][cc] + b1v[cc];
                const float g = z / (1.f + __expf(-z));
                s = fmaf(g, w2v[cc], s);
            }
            sv[u] = dpp_sum16(s);
        }

        if (((lane & 15) == 15) && n < N) {
            const float bb2 = b2[0];
            const int bidx = batch[n];
            const int cb = bcnt[bidx];
            const float ic = 1.f / (float)(cb > 0 ? cb : 1);
            const int base = bidx * 9;
            const float v0 = (sv[0] + bb2) * ic;
            const float v1 = (sv[1] + bb2) * ic;
            const float v2 = (sv[2] + bb2) * ic;
            const float v3 = (sv[3] + bb2) * ic;
            const float v4 = (sv[4] + bb2) * ic;
            const float v5 = (sv[5] + bb2) * ic;
            atomicAdd(&out[base + 0], v0);
            atomicAdd(&out[base + 1], v1);
            atomicAdd(&out[base + 2], v2);
            atomicAdd(&out[base + 3], v1);
            atomicAdd(&out[base + 4], v3);
            atomicAdd(&out[base + 5], v4);
            atomicAdd(&out[base + 6], v2);
            atomicAdd(&out[base + 7], v4);
            atomicAdd(&out[base + 8], v5);
        }
    }
}

extern "C" void kernel_launch(void* const* d_in, const int* in_sizes, int n_in,
                              void* d_out, int out_size, void* d_ws, size_t ws_size,
                              hipStream_t stream) {
    const float* emb   = (const float*)d_in[0];
    const float* vec   = (const float*)d_in[1];
    const int*   eidx  = (const int*)  d_in[2];
    const int*   batch = (const int*)  d_in[3];
    const float* sph_w = (const float*)d_in[4];
    const float* ln_w  = (const float*)d_in[5];
    const float* ln_b  = (const float*)d_in[6];
    const float* W1    = (const float*)d_in[7];
    const float* b1    = (const float*)d_in[8];
    const float* W2    = (const float*)d_in[9];
    const float* b2    = (const float*)d_in[10];

    const int N = in_sizes[3];
    const int E = in_sizes[1] / 3;
    const int B = out_size / 9;
    const int* idx1 = eidx + E;   // edge_index[1]

    // ws: [cnt N][bcnt B][elist N*slot][stats N*56]
    int slot = 64;
    {
        const size_t base = (size_t)(N + B) + (size_t)N * 56;
        while (slot > 1 && (base + (size_t)N * slot) * 4 > ws_size) slot >>= 1;
    }
    int*   cnt   = (int*)d_ws;
    int*   bcnt  = cnt + N;
    int*   elist = bcnt + B;
    float* stats = (float*)(elist + (size_t)N * slot);

    hipMemsetAsync(d_out, 0, (size_t)out_size * sizeof(float), stream);
    hipMemsetAsync(cnt, 0, (size_t)(N + B) * sizeof(int), stream);

    const int PB = (max((E + 3) / 4, N) + 255) / 256;
    const int SB = (N + 3) / 4;
    prep_kernel<<<PB + SB, 256, 0, stream>>>(idx1, batch, cnt, bcnt, elist,
                                             emb, stats, slot, E, N, PB);
    fused_kernel<<<(N + NB - 1) / NB, 256, 0, stream>>>(
        emb, vec, cnt, elist, slot, sph_w, stats, ln_w, ln_b,
        W1, b1, W2, b2, batch, bcnt, (float*)d_out, N);
}